// Round 3
// baseline (720.855 us; speedup 1.0000x reference)
//
#include <hip/hip_runtime.h>
#include <hip/hip_bf16.h>
#include <math.h>

// HNNLayer for MI355X, two-stage streaming design (no LDS, no barriers):
//  prep:     W[1:,1:] -> bf16 Wb[256x256], bias-transport scalars
//  prologue: t = acosh(h0)*y/||y||, tn = LN(t)*gamma+beta -> Xb (bf16)
//  gemm_epi: v = tn @ Wb^T via MFMA (A,B direct from global), hyperbolic epilogue
// expmap0/logmap0 round trips are exact identities and are elided.

#define MINV 1e-15f

typedef __bf16 bf16x8 __attribute__((ext_vector_type(8)));
typedef __bf16 bf16x4 __attribute__((ext_vector_type(4)));
typedef float floatx4 __attribute__((ext_vector_type(4)));

// ---- prep: Wb[j][k] = W[j+1][k] (row 255 zero), plus epilogue scalars ----
__global__ __launch_bounds__(256) void prep_kernel(const float* __restrict__ W,
                                                   const float* __restrict__ bias,
                                                   __bf16* __restrict__ Wb,
                                                   float* __restrict__ scal) {
  int b = blockIdx.x;
  if (b < 64) {
    int idx = b * 1024 + threadIdx.x * 4;
    int j = idx >> 8;
    float4 w;
    if (j < 255) w = *(const float4*)(W + idx + 256);
    else w = make_float4(0.f, 0.f, 0.f, 0.f);
    bf16x4 o;
    o[0] = (__bf16)w.x; o[1] = (__bf16)w.y; o[2] = (__bf16)w.z; o[3] = (__bf16)w.w;
    *(bf16x4*)(Wb + idx) = o;
  } else if (threadIdx.x < 64) {
    int l = threadIdx.x;
    float4 bv = *(const float4*)(bias + l * 4);
    float s = bv.x * bv.x + bv.y * bv.y + bv.z * bv.z + bv.w * bv.w;
    if (l == 0) s -= bv.x * bv.x;
    for (int m = 1; m < 64; m <<= 1) s += __shfl_xor(s, m);
    if (l == 0) {
      float nb = sqrtf(s);
      float normu = fminf(nb, 1000.0f);
      float th = fmaxf(normu, MINV);
      scal[0] = coshf(th);          // c1
      scal[1] = sinhf(th) / th;     // s1
      scal[2] = s;                  // ||b1||^2
    }
  }
}

// ---- prologue: 128 rows/block, 32 rows/wave, 4 rows concurrently (16 lanes/row) ----
__global__ __launch_bounds__(256, 4) void prologue_kernel(const float* __restrict__ h,
                                                          const float* __restrict__ gamma,
                                                          const float* __restrict__ beta,
                                                          __bf16* __restrict__ Xb) {
  const int lane = threadIdx.x & 63;
  const int wave = threadIdx.x >> 6;
  const int lane16 = lane & 15;
  const int quad = lane >> 4;

  // lane owns cols c = q*64 + lane16*4 + i  (i=0..3, q=0..3); col 0 -> g=be=0
  float g[16], be[16];
#pragma unroll
  for (int q = 0; q < 4; ++q)
#pragma unroll
    for (int i = 0; i < 4; ++i) {
      int c = q * 64 + lane16 * 4 + i;
      g[q * 4 + i]  = (c > 0) ? gamma[c - 1] : 0.f;
      be[q * 4 + i] = (c > 0) ? beta[c - 1]  : 0.f;
    }

  const int rowBase = blockIdx.x * 128 + wave * 32;
#pragma unroll 2
  for (int it = 0; it < 8; ++it) {
    const int row = rowBase + it * 4 + quad;
    const float* hrow = h + (size_t)row * 256;
    float vals[16];
#pragma unroll
    for (int q = 0; q < 4; ++q) {
      float4 hv = *(const float4*)(hrow + q * 64 + lane16 * 4);
      vals[q * 4 + 0] = hv.x; vals[q * 4 + 1] = hv.y;
      vals[q * 4 + 2] = hv.z; vals[q * 4 + 3] = hv.w;
    }
    float s1l = 0.f, s2l = 0.f;
#pragma unroll
    for (int i = 0; i < 16; ++i) { s1l += vals[i]; s2l += vals[i] * vals[i]; }
    if (lane16 == 0) { s1l -= vals[0]; s2l -= vals[0] * vals[0]; }  // exclude col 0
#pragma unroll
    for (int m = 1; m < 16; m <<= 1) {
      s1l += __shfl_xor(s1l, m);
      s2l += __shfl_xor(s2l, m);
    }
    float h0 = __shfl(vals[0], lane & 48);        // col-0 value (group base lane)
    float yn = fmaxf(sqrtf(s2l), MINV);
    float xc = fmaxf(h0, 1.0f + 1e-7f);
    float theta = __logf(xc + sqrtf(xc * xc - 1.0f));   // acosh; post-LN precision-safe
    float s = theta / yn;
    float mu = s * s1l * (1.0f / 255.0f);
    float var = s * s * (s2l * (1.0f / 255.0f)) - mu * mu;
    float rstd = rsqrtf(var + 1e-5f);
    float a = s * rstd;
    float bshift = -mu * rstd;
    __bf16* xrow = Xb + (size_t)row * 256;
#pragma unroll
    for (int q = 0; q < 4; ++q) {
      bf16x4 o;
#pragma unroll
      for (int i = 0; i < 4; ++i)
        o[i] = (__bf16)((a * vals[q * 4 + i] + bshift) * g[q * 4 + i] + be[q * 4 + i]);
      *(bf16x4*)(xrow + q * 64 + lane16 * 4) = o;
    }
  }
}

// ---- gemm+epilogue: 64 rows/block, 16 rows/wave, no LDS, no barriers ----
__global__ __launch_bounds__(256, 3) void gemm_epi_kernel(const __bf16* __restrict__ Xb,
                                                          const __bf16* __restrict__ Wb,
                                                          const float* __restrict__ bias,
                                                          const float* __restrict__ scal,
                                                          float* __restrict__ out) {
  const int lane = threadIdx.x & 63;
  const int wave = threadIdx.x >> 6;
  const int lane16 = lane & 15;
  const int quad = lane >> 4;
  const int rowBase = blockIdx.x * 64 + wave * 16;

  // A fragments direct from global (rows are this wave's 16 rows)
  const __bf16* arow = Xb + (size_t)(rowBase + lane16) * 256 + quad * 8;
  bf16x8 afr[8];
#pragma unroll
  for (int kk = 0; kk < 8; ++kk) afr[kk] = *(const bf16x8*)(arow + kk * 32);

  floatx4 acc[16];
#pragma unroll
  for (int jt = 0; jt < 16; ++jt) acc[jt] = (floatx4){0.f, 0.f, 0.f, 0.f};

  const __bf16* wbase = Wb + lane16 * 256 + quad * 8;
#pragma unroll
  for (int kk = 0; kk < 8; ++kk) {
#pragma unroll
    for (int jt = 0; jt < 16; ++jt) {
      bf16x8 bfr = *(const bf16x8*)(wbase + jt * 4096 + kk * 32);
      acc[jt] = __builtin_amdgcn_mfma_f32_16x16x32_bf16(afr[kk], bfr, acc[jt], 0, 0, 0);
    }
  }

  // ---- hyperbolic epilogue ----
  const float c1 = scal[0];
  const float s1s = scal[1];
  const float tb2 = scal[2];

  float bb1[16];
#pragma unroll
  for (int jt = 0; jt < 16; ++jt) {
    int j = jt * 16 + lane16;
    bb1[jt] = (j < 255) ? bias[j + 1] : 0.f;
  }

#pragma unroll
  for (int e = 0; e < 4; ++e) {
    float* orow = out + (size_t)(rowBase + quad * 4 + e) * 256;
    float sv2 = 0.f, svb = 0.f;
#pragma unroll
    for (int jt = 0; jt < 16; ++jt) {
      float v = acc[jt][e];
      sv2 += v * v;
      svb += v * bb1[jt];
    }
#pragma unroll
    for (int m = 1; m < 16; m <<= 1) {
      sv2 += __shfl_xor(sv2, m);
      svb += __shfl_xor(svb, m);
    }
    float n = fmaxf(sqrtf(sv2), MINV);
    float inv_n = 1.0f / n;
    float alpha = svb * inv_n;
    float ex = __expf(n);
    float iex = 1.0f / ex;
    float ch = 0.5f * (ex + iex), sh = 0.5f * (ex - iex);
    float beta_ = c1 * sh + s1s * alpha * (ch - 1.0f);
    float rn2 = beta_ * beta_ + 2.0f * beta_ * s1s * alpha + s1s * s1s * tb2;
    float rn = sqrtf(fmaxf(rn2, 0.f));
    float res0 = sqrtf(1.0f + rn2);
    float th3 = __logf(res0 + rn);               // acosh(sqrt(1+rn2))
    float sc3 = th3 / fmaxf(rn, MINV);
    float cvn = beta_ * inv_n;

    float sx2 = 0.f;
#pragma unroll
    for (int jt = 0; jt < 16; ++jt) {
      float x = fmaxf(sc3 * (cvn * acc[jt][e] + s1s * bb1[jt]), 0.f);
      sx2 += x * x;
    }
#pragma unroll
    for (int m = 1; m < 16; m <<= 1) sx2 += __shfl_xor(sx2, m);
    float n2 = fmaxf(sqrtf(sx2), MINV);
    float e2 = __expf(n2);
    float ie2 = 1.0f / e2;
    float scl = 0.5f * (e2 - ie2) / n2;          // sinh(n2)/n2

#pragma unroll
    for (int jt = 0; jt < 16; ++jt) {
      float x = fmaxf(sc3 * (cvn * acc[jt][e] + s1s * bb1[jt]), 0.f);
      int j = jt * 16 + lane16;
      if (j < 255) orow[j + 1] = scl * x;
    }
    if (lane16 == 0) orow[0] = 0.5f * (e2 + ie2);
  }
}

extern "C" void kernel_launch(void* const* d_in, const int* in_sizes, int n_in,
                              void* d_out, int out_size, void* d_ws, size_t ws_size,
                              hipStream_t stream) {
  const float* h     = (const float*)d_in[0];
  const float* W     = (const float*)d_in[1];
  const float* bias  = (const float*)d_in[2];
  const float* gamma = (const float*)d_in[3];
  const float* beta  = (const float*)d_in[4];
  float* out = (float*)d_out;

  __bf16* Wb  = (__bf16*)d_ws;                           // 128 KiB
  float* scal = (float*)((char*)d_ws + 131072);          // 3 floats
  __bf16* Xb  = (__bf16*)((char*)d_ws + 262144);         // 128 MiB

  prep_kernel<<<dim3(65), dim3(256), 0, stream>>>(W, bias, Wb, scal);
  prologue_kernel<<<dim3(2048), dim3(256), 0, stream>>>(h, gamma, beta, Xb);
  gemm_epi_kernel<<<dim3(4096), dim3(256), 0, stream>>>(Xb, Wb, bias, scal, out);
}